// Round 1
// baseline (110.469 us; speedup 1.0000x reference)
//
#include <hip/hip_runtime.h>
#include <cmath>

// Problem geometry (fixed by the reference):
static constexpr int BATCH = 2048;
static constexpr int K = 64 * 1024;   // T*H = 65536
static constexpr int K4 = K / 4;      // float4 count per row

// ---------------------------------------------------------------------------
// Kernel A: w_clip = max |w| over the 65536-element weight vector.
// Single block of 1024 threads; coalesced float4 reads; wave shuffle reduce
// then a tiny serial reduce over the 16 per-wave partials. Deterministic.
// ---------------------------------------------------------------------------
__global__ __launch_bounds__(1024)
void wmax_kernel(const float* __restrict__ w, float* __restrict__ wmax_out) {
    const int tid = threadIdx.x;
    const float4* w4 = reinterpret_cast<const float4*>(w);
    float m = 0.0f;
    for (int i = tid; i < K4; i += 1024) {
        float4 v = w4[i];
        m = fmaxf(m, fmaxf(fmaxf(fabsf(v.x), fabsf(v.y)),
                           fmaxf(fabsf(v.z), fabsf(v.w))));
    }
#pragma unroll
    for (int off = 32; off > 0; off >>= 1)
        m = fmaxf(m, __shfl_down(m, off, 64));
    __shared__ float sm[16];
    if ((tid & 63) == 0) sm[tid >> 6] = m;
    __syncthreads();
    if (tid == 0) {
        float r = sm[0];
#pragma unroll
        for (int i = 1; i < 16; ++i) r = fmaxf(r, sm[i]);
        wmax_out[0] = r;
    }
}

// ---------------------------------------------------------------------------
// Kernel B: fused fake-quant(x) . fake-quant(w) GEMV + bias + tanh.
// One block per batch row, 256 threads, float4-strided coalesced loads.
// Quantization done in integer space: qx,qw in [-127,127] held as floats
// (exact); acc accumulates qx*qw (exact integer products); final scale
// s_x*s_w applied once. round-half-even via rintf matches jnp.round/np.round.
// ---------------------------------------------------------------------------
__global__ __launch_bounds__(256)
void gemv_quant_tanh_kernel(const float* __restrict__ x,
                            const float* __restrict__ w,
                            const float* __restrict__ bias,
                            const float* __restrict__ clip,
                            const float* __restrict__ wmax,
                            float* __restrict__ out) {
    const int row = blockIdx.x;
    const int tid = threadIdx.x;

    const float cx = fabsf(clip[0]);
    const float sx = cx * (1.0f / 127.0f);   // activation quant scale
    const float ix = 127.0f / cx;            // inverse scale
    const float cw = wmax[0];
    const float sw = cw * (1.0f / 127.0f);   // weight quant scale
    const float iw = 127.0f / cw;

    const float4* xr = reinterpret_cast<const float4*>(x + (size_t)row * K);
    const float4* w4 = reinterpret_cast<const float4*>(w);

    float acc = 0.0f;
    for (int i = tid; i < K4; i += 256) {
        float4 xv = xr[i];
        float4 wv = w4[i];
        float qx0 = rintf(fminf(fmaxf(xv.x, -cx), cx) * ix);
        float qx1 = rintf(fminf(fmaxf(xv.y, -cx), cx) * ix);
        float qx2 = rintf(fminf(fmaxf(xv.z, -cx), cx) * ix);
        float qx3 = rintf(fminf(fmaxf(xv.w, -cx), cx) * ix);
        float qw0 = rintf(fminf(fmaxf(wv.x, -cw), cw) * iw);
        float qw1 = rintf(fminf(fmaxf(wv.y, -cw), cw) * iw);
        float qw2 = rintf(fminf(fmaxf(wv.z, -cw), cw) * iw);
        float qw3 = rintf(fminf(fmaxf(wv.w, -cw), cw) * iw);
        acc = fmaf(qx0, qw0, acc);
        acc = fmaf(qx1, qw1, acc);
        acc = fmaf(qx2, qw2, acc);
        acc = fmaf(qx3, qw3, acc);
    }

    // block reduction: wave64 shuffle then 4 partials through LDS
#pragma unroll
    for (int off = 32; off > 0; off >>= 1)
        acc += __shfl_down(acc, off, 64);
    __shared__ float sm[4];
    if ((tid & 63) == 0) sm[tid >> 6] = acc;
    __syncthreads();
    if (tid == 0) {
        float s = (sm[0] + sm[1]) + (sm[2] + sm[3]);
        out[row] = tanhf(fmaf(s, sx * sw, bias[0]));
    }
}

extern "C" void kernel_launch(void* const* d_in, const int* in_sizes, int n_in,
                              void* d_out, int out_size, void* d_ws, size_t ws_size,
                              hipStream_t stream) {
    const float* x    = (const float*)d_in[0];  // hidden_states [2048,64,1024]
    const float* w    = (const float*)d_in[1];  // weight [1, 65536]
    const float* bias = (const float*)d_in[2];  // [1]
    const float* clip = (const float*)d_in[3];  // scalar
    float* out  = (float*)d_out;                // [2048] fp32
    float* wmax = (float*)d_ws;                 // 4 bytes of scratch

    wmax_kernel<<<1, 1024, 0, stream>>>(w, wmax);
    gemv_quant_tanh_kernel<<<BATCH, 256, 0, stream>>>(x, w, bias, clip, wmax, out);
}

// Round 3
// 102.250 us; speedup vs baseline: 1.0804x; 1.0804x over previous
//
#include <hip/hip_runtime.h>
#include <cmath>

// Problem geometry (fixed by the reference):
static constexpr int BATCH = 2048;
static constexpr int K = 64 * 1024;   // T*H = 65536
static constexpr int K4 = K / 4;      // float4 count per row

typedef float f4 __attribute__((ext_vector_type(4)));  // clang-native vec4

// ---------------------------------------------------------------------------
// Kernel A: w_clip = max |w|, parallel across 32 blocks.
// abs(float) >= 0, so the uint bit pattern preserves ordering -> atomicMax
// on uint is exact and order-independent (deterministic). ws[0] must be
// zeroed before launch (done via hipMemsetAsync in kernel_launch).
// ---------------------------------------------------------------------------
__global__ __launch_bounds__(256)
void wmax_kernel(const float* __restrict__ w, unsigned int* __restrict__ wmax_bits) {
    const int tid = blockIdx.x * 256 + threadIdx.x;          // 8192 threads
    const f4* w4 = reinterpret_cast<const f4*>(w);
    float m = 0.0f;
#pragma unroll
    for (int r = 0; r < 2; ++r) {                            // 16384 float4s total
        f4 v = w4[tid + r * 8192];
        m = fmaxf(m, fmaxf(fmaxf(fabsf(v.x), fabsf(v.y)),
                           fmaxf(fabsf(v.z), fabsf(v.w))));
    }
#pragma unroll
    for (int off = 32; off > 0; off >>= 1)
        m = fmaxf(m, __shfl_down(m, off, 64));
    if ((threadIdx.x & 63) == 0)
        atomicMax(wmax_bits, __float_as_uint(m));
}

// ---------------------------------------------------------------------------
// Kernel B: fused fake-quant(x) . fake-quant(w) GEMV + bias + tanh.
// One block per batch row, 256 threads, nontemporal float4 streaming loads
// for x (no reuse; keeps the hot 256 KiB weight vector resident in L2).
// Quantization in integer space (exact products <= 127^2), scales folded
// into one multiply at the end. rintf == round-half-even == jnp.round.
// The weight clamp is a no-op (clip == max|w|) and is omitted.
// ---------------------------------------------------------------------------
__global__ __launch_bounds__(256)
void gemv_quant_tanh_kernel(const float* __restrict__ x,
                            const float* __restrict__ w,
                            const float* __restrict__ bias,
                            const float* __restrict__ clip,
                            const unsigned int* __restrict__ wmax_bits,
                            float* __restrict__ out) {
    const int row = blockIdx.x;
    const int tid = threadIdx.x;

    const float cx = fabsf(clip[0]);
    const float sx = cx * (1.0f / 127.0f);   // activation quant scale
    const float ix = 127.0f / cx;            // inverse scale
    const float cw = __uint_as_float(wmax_bits[0]);
    const float sw = cw * (1.0f / 127.0f);   // weight quant scale
    const float iw = 127.0f / cw;

    const f4* xr = reinterpret_cast<const f4*>(x + (size_t)row * K);
    const f4* w4 = reinterpret_cast<const f4*>(w);

    float acc = 0.0f;
#pragma unroll 4
    for (int i = tid; i < K4; i += 256) {
        f4 xv = __builtin_nontemporal_load(&xr[i]);
        f4 wv = w4[i];
        float qx0 = rintf(fminf(fmaxf(xv.x, -cx), cx) * ix);
        float qx1 = rintf(fminf(fmaxf(xv.y, -cx), cx) * ix);
        float qx2 = rintf(fminf(fmaxf(xv.z, -cx), cx) * ix);
        float qx3 = rintf(fminf(fmaxf(xv.w, -cx), cx) * ix);
        float qw0 = rintf(wv.x * iw);
        float qw1 = rintf(wv.y * iw);
        float qw2 = rintf(wv.z * iw);
        float qw3 = rintf(wv.w * iw);
        acc = fmaf(qx0, qw0, acc);
        acc = fmaf(qx1, qw1, acc);
        acc = fmaf(qx2, qw2, acc);
        acc = fmaf(qx3, qw3, acc);
    }

    // block reduction: wave64 shuffle then 4 partials through LDS
#pragma unroll
    for (int off = 32; off > 0; off >>= 1)
        acc += __shfl_down(acc, off, 64);
    __shared__ float sm[4];
    if ((tid & 63) == 0) sm[tid >> 6] = acc;
    __syncthreads();
    if (tid == 0) {
        float s = (sm[0] + sm[1]) + (sm[2] + sm[3]);
        out[row] = tanhf(fmaf(s, sx * sw, bias[0]));
    }
}

extern "C" void kernel_launch(void* const* d_in, const int* in_sizes, int n_in,
                              void* d_out, int out_size, void* d_ws, size_t ws_size,
                              hipStream_t stream) {
    const float* x    = (const float*)d_in[0];  // hidden_states [2048,64,1024]
    const float* w    = (const float*)d_in[1];  // weight [1, 65536]
    const float* bias = (const float*)d_in[2];  // [1]
    const float* clip = (const float*)d_in[3];  // scalar
    float* out = (float*)d_out;                 // [2048] fp32
    unsigned int* wmax_bits = (unsigned int*)d_ws;

    (void)hipMemsetAsync(wmax_bits, 0, sizeof(unsigned int), stream);
    wmax_kernel<<<32, 256, 0, stream>>>(w, wmax_bits);
    gemv_quant_tanh_kernel<<<BATCH, 256, 0, stream>>>(x, w, bias, clip, wmax_bits, out);
}

// Round 4
// 86.396 us; speedup vs baseline: 1.2786x; 1.1835x over previous
//
#include <hip/hip_runtime.h>
#include <cmath>

// Problem geometry (fixed by the reference):
static constexpr int BATCH = 2048;
static constexpr int K = 64 * 1024;   // T*H = 65536
static constexpr int K4 = K / 4;      // float4 count per row

typedef float f4 __attribute__((ext_vector_type(4)));  // clang-native vec4

// Workspace layout (new path): [0..128) 32 float partial maxes; [256..65792) packed int8 qw.
static constexpr size_t WS_NEEDED = 256 + (size_t)K;   // 65792 bytes

// ---------------------------------------------------------------------------
// Kernel A: 32 per-block partial maxes of |w|, plain stores (no atomics, no
// memset needed). Downstream kernels reduce the 32 floats in their prologue.
// ---------------------------------------------------------------------------
__global__ __launch_bounds__(256)
void wmax_part_kernel(const float* __restrict__ w, float* __restrict__ wpart) {
    const int tid = blockIdx.x * 256 + threadIdx.x;          // 8192 threads
    const f4* w4 = reinterpret_cast<const f4*>(w);
    float m = 0.0f;
#pragma unroll
    for (int r = 0; r < 2; ++r) {                            // 16384 float4s
        f4 v = w4[tid + r * 8192];
        m = fmaxf(m, fmaxf(fmaxf(fabsf(v.x), fabsf(v.y)),
                           fmaxf(fabsf(v.z), fabsf(v.w))));
    }
#pragma unroll
    for (int off = 32; off > 0; off >>= 1)
        m = fmaxf(m, __shfl_down(m, off, 64));
    __shared__ float sm[4];
    if ((threadIdx.x & 63) == 0) sm[threadIdx.x >> 6] = m;
    __syncthreads();
    if (threadIdx.x == 0)
        wpart[blockIdx.x] = fmaxf(fmaxf(sm[0], sm[1]), fmaxf(sm[2], sm[3]));
}

// ---------------------------------------------------------------------------
// Kernel A2: quantize w to packed int8 (4 per dword). |w| <= cw so no clamp
// needed; rintf == round-half-even == jnp.round. 64 KiB output, L2-resident.
// ---------------------------------------------------------------------------
__global__ __launch_bounds__(256)
void wquant_kernel(const float* __restrict__ w, const float* __restrict__ wpart,
                   unsigned int* __restrict__ qw) {
    float cw = 0.0f;
#pragma unroll
    for (int i = 0; i < 32; ++i) cw = fmaxf(cw, wpart[i]);
    const float iw = 127.0f / cw;
    const int t = blockIdx.x * 256 + threadIdx.x;            // 4096 threads
    const f4* w4 = reinterpret_cast<const f4*>(w);
#pragma unroll
    for (int r = 0; r < 4; ++r) {
        int idx = t + r * 4096;
        f4 v = w4[idx];
        int q0 = (int)rintf(v.x * iw), q1 = (int)rintf(v.y * iw);
        int q2 = (int)rintf(v.z * iw), q3 = (int)rintf(v.w * iw);
        qw[idx] = (unsigned int)((q0 & 0xff) | ((q1 & 0xff) << 8) |
                                 ((q2 & 0xff) << 16) | ((q3 & 0xff) << 24));
    }
}

// ---------------------------------------------------------------------------
// Kernel B: fused fake-quant GEMV + bias + tanh. One block per row.
// Deep manual unroll: 8 nontemporal x-float4 loads + 8 qw dwords issued
// back-to-back per outer iteration to maximize loads in flight (MLP).
// Integer-space accumulation (exact products), scales folded at the end.
// ---------------------------------------------------------------------------
__global__ __launch_bounds__(256)
void gemv_quant_tanh_kernel(const float* __restrict__ x,
                            const unsigned int* __restrict__ qw,
                            const float* __restrict__ bias,
                            const float* __restrict__ clip,
                            const float* __restrict__ wpart,
                            float* __restrict__ out) {
    const int row = blockIdx.x;
    const int tid = threadIdx.x;

    float cw = 0.0f;
#pragma unroll
    for (int i = 0; i < 32; ++i) cw = fmaxf(cw, wpart[i]);
    const float cx = fabsf(clip[0]);
    const float ix = 127.0f / cx;
    const float scale = (cx / 127.0f) * (cw / 127.0f);  // sx * sw

    const f4* xr = reinterpret_cast<const f4*>(x + (size_t)row * K);

    float acc = 0.0f;
    for (int outer = 0; outer < 8; ++outer) {
        const int base = outer * 2048 + tid;
        f4 xv[8];
        unsigned int qv[8];
#pragma unroll
        for (int u = 0; u < 8; ++u)
            xv[u] = __builtin_nontemporal_load(&xr[base + u * 256]);
#pragma unroll
        for (int u = 0; u < 8; ++u)
            qv[u] = qw[base + u * 256];
#pragma unroll
        for (int u = 0; u < 8; ++u) {
            f4 v = xv[u];
            unsigned int q = qv[u];
            float qx0 = rintf(__builtin_amdgcn_fmed3f(v.x, -cx, cx) * ix);
            float qx1 = rintf(__builtin_amdgcn_fmed3f(v.y, -cx, cx) * ix);
            float qx2 = rintf(__builtin_amdgcn_fmed3f(v.z, -cx, cx) * ix);
            float qx3 = rintf(__builtin_amdgcn_fmed3f(v.w, -cx, cx) * ix);
            float w0 = (float)((int)(q << 24) >> 24);
            float w1 = (float)((int)(q << 16) >> 24);
            float w2 = (float)((int)(q <<  8) >> 24);
            float w3 = (float)((int)q >> 24);
            acc = fmaf(qx0, w0, acc);
            acc = fmaf(qx1, w1, acc);
            acc = fmaf(qx2, w2, acc);
            acc = fmaf(qx3, w3, acc);
        }
    }

    // block reduction: wave64 shuffle then 4 partials through LDS
#pragma unroll
    for (int off = 32; off > 0; off >>= 1)
        acc += __shfl_down(acc, off, 64);
    __shared__ float sm[4];
    if ((tid & 63) == 0) sm[tid >> 6] = acc;
    __syncthreads();
    if (tid == 0) {
        float s = (sm[0] + sm[1]) + (sm[2] + sm[3]);
        out[row] = tanhf(fmaf(s, scale, bias[0]));
    }
}

// ---------------------------------------------------------------------------
// Fallback path (round-3 kernels) if ws_size is too small for the qw buffer.
// ---------------------------------------------------------------------------
__global__ __launch_bounds__(256)
void wmax_atomic_kernel(const float* __restrict__ w, unsigned int* __restrict__ wmax_bits) {
    const int tid = blockIdx.x * 256 + threadIdx.x;
    const f4* w4 = reinterpret_cast<const f4*>(w);
    float m = 0.0f;
#pragma unroll
    for (int r = 0; r < 2; ++r) {
        f4 v = w4[tid + r * 8192];
        m = fmaxf(m, fmaxf(fmaxf(fabsf(v.x), fabsf(v.y)),
                           fmaxf(fabsf(v.z), fabsf(v.w))));
    }
#pragma unroll
    for (int off = 32; off > 0; off >>= 1)
        m = fmaxf(m, __shfl_down(m, off, 64));
    if ((threadIdx.x & 63) == 0)
        atomicMax(wmax_bits, __float_as_uint(m));
}

__global__ __launch_bounds__(256)
void gemv_fallback_kernel(const float* __restrict__ x, const float* __restrict__ w,
                          const float* __restrict__ bias, const float* __restrict__ clip,
                          const unsigned int* __restrict__ wmax_bits,
                          float* __restrict__ out) {
    const int row = blockIdx.x;
    const int tid = threadIdx.x;
    const float cx = fabsf(clip[0]);
    const float ix = 127.0f / cx;
    const float cw = __uint_as_float(wmax_bits[0]);
    const float iw = 127.0f / cw;
    const float scale = (cx / 127.0f) * (cw / 127.0f);
    const f4* xr = reinterpret_cast<const f4*>(x + (size_t)row * K);
    const f4* w4 = reinterpret_cast<const f4*>(w);
    float acc = 0.0f;
#pragma unroll 4
    for (int i = tid; i < K4; i += 256) {
        f4 xv = __builtin_nontemporal_load(&xr[i]);
        f4 wv = w4[i];
        float qx0 = rintf(__builtin_amdgcn_fmed3f(xv.x, -cx, cx) * ix);
        float qx1 = rintf(__builtin_amdgcn_fmed3f(xv.y, -cx, cx) * ix);
        float qx2 = rintf(__builtin_amdgcn_fmed3f(xv.z, -cx, cx) * ix);
        float qx3 = rintf(__builtin_amdgcn_fmed3f(xv.w, -cx, cx) * ix);
        acc = fmaf(qx0, rintf(wv.x * iw), acc);
        acc = fmaf(qx1, rintf(wv.y * iw), acc);
        acc = fmaf(qx2, rintf(wv.z * iw), acc);
        acc = fmaf(qx3, rintf(wv.w * iw), acc);
    }
#pragma unroll
    for (int off = 32; off > 0; off >>= 1)
        acc += __shfl_down(acc, off, 64);
    __shared__ float sm[4];
    if ((tid & 63) == 0) sm[tid >> 6] = acc;
    __syncthreads();
    if (tid == 0) {
        float s = (sm[0] + sm[1]) + (sm[2] + sm[3]);
        out[row] = tanhf(fmaf(s, scale, bias[0]));
    }
}

extern "C" void kernel_launch(void* const* d_in, const int* in_sizes, int n_in,
                              void* d_out, int out_size, void* d_ws, size_t ws_size,
                              hipStream_t stream) {
    const float* x    = (const float*)d_in[0];  // hidden_states [2048,64,1024]
    const float* w    = (const float*)d_in[1];  // weight [1, 65536]
    const float* bias = (const float*)d_in[2];  // [1]
    const float* clip = (const float*)d_in[3];  // scalar
    float* out = (float*)d_out;                 // [2048] fp32

    if (ws_size >= WS_NEEDED) {
        float* wpart = (float*)d_ws;                                  // 32 floats
        unsigned int* qw = (unsigned int*)((char*)d_ws + 256);        // 64 KiB
        wmax_part_kernel<<<32, 256, 0, stream>>>(w, wpart);
        wquant_kernel<<<16, 256, 0, stream>>>(w, wpart, qw);
        gemv_quant_tanh_kernel<<<BATCH, 256, 0, stream>>>(x, qw, bias, clip, wpart, out);
    } else {
        unsigned int* wmax_bits = (unsigned int*)d_ws;
        (void)hipMemsetAsync(wmax_bits, 0, sizeof(unsigned int), stream);
        wmax_atomic_kernel<<<32, 256, 0, stream>>>(w, wmax_bits);
        gemv_fallback_kernel<<<BATCH, 256, 0, stream>>>(x, w, bias, clip, wmax_bits, out);
    }
}